// Round 1
// baseline (6188.332 us; speedup 1.0000x reference)
//
#include <hip/hip_runtime.h>
#include <hip/hip_bf16.h>
#include <stdint.h>

// ---------- problem constants (fixed by setup_inputs) ----------
#define H_  2048      // hidden
#define I_  1024      // intermediate
#define E_  32        // experts
#define T_  8192      // tokens (4*2048)
#define A_  16384     // assignments (T*top_k)
#define MT_MAX 32     // max 128-row m-tiles per (expert,slot) segment

typedef unsigned short u16;
typedef u16  u16x8 __attribute__((ext_vector_type(8)));
typedef __bf16 bf16x8 __attribute__((ext_vector_type(8)));
typedef float f32x4 __attribute__((ext_vector_type(4)));
typedef float f32x8 __attribute__((ext_vector_type(8)));

// native RTNE f32->bf16 (compiles to v_cvt_pk_bf16_f32; identical rounding
// to the old manual round-half-to-even bit trick, ~6x fewer VALU instrs)
__device__ __forceinline__ u16 f2bf(float f) {
  union { __bf16 b; u16 u; } w; w.b = (__bf16)f; return w.u;
}
__device__ __forceinline__ u16x8 cvt8(f32x4 a, f32x4 b) {
  f32x8 f;
  #pragma unroll
  for (int i = 0; i < 4; i++) { f[i] = a[i]; f[i+4] = b[i]; }
  union { bf16x8 h; u16x8 u; } w;
  w.h = __builtin_convertvector(f, bf16x8);
  return w.u;
}

// swizzled u16 index for (row, 8-col-group cc) in a [rows][64]-u16 LDS tile.
// Row stride is 128B: unswizzled, 16 lanes reading different rows at the same
// col-group all land in one 4-bank group (16-way conflict). XOR'ing the group
// with (row&7) spreads them across 8 groups -> 2-way (free per m136).
__device__ __forceinline__ int swz(int r, int cc) {
  return (r << 6) + ((cc ^ (r & 7)) << 3);
}

// ---------- workspace layout (bytes), total 33,817,600 (~33.8 MB) ----------
// 0      : counts2[64] int   (index = expert*2 + slot)
// 256    : cursor2[64] int
// 512    : eoff[33]    int
// 768    : c0arr[32]   int
// 1024   : topk_e[A_]  int    -> 66560
// 66560  : topk_g[A_]  float  -> 132096
// 132096 : rows[A_]    int    -> 197632
// 197632 : gval[A_]    float  -> 263168
// 263168 : h[A_*I_]    bf16   -> 33817600

__global__ void k_zero(int* p) { p[threadIdx.x] = 0; }

// ---------- kernel 1: router (f32 in, f32 math) ----------
// block = 256 threads = 8 tokens x 32 experts. grid = T/8.
__global__ __launch_bounds__(256) void k_router(
    const float* __restrict__ x, const float* __restrict__ gw, const float* __restrict__ gb,
    int* __restrict__ counts2, int* __restrict__ topk_e, float* __restrict__ topk_g)
{
  int tid = threadIdx.x;
  int tt = tid >> 5;          // token within block
  int e  = tid & 31;          // expert
  int t  = blockIdx.x * 8 + tt;
  const float* xp = x  + (size_t)t * H_;
  const float* wp = gw + (size_t)e * H_;
  float acc = 0.f;
  for (int k = 0; k < H_; k += 8) {
    f32x4 x0 = *(const f32x4*)(xp + k);
    f32x4 x1 = *(const f32x4*)(xp + k + 4);
    f32x4 w0 = *(const f32x4*)(wp + k);
    f32x4 w1v = *(const f32x4*)(wp + k + 4);
    #pragma unroll
    for (int i = 0; i < 4; i++) acc += x0[i]*w0[i] + x1[i]*w1v[i];
  }
  float logit = acc + gb[e];
  // softmax over the 32-lane group
  float mx = logit;
  #pragma unroll
  for (int m = 16; m; m >>= 1) mx = fmaxf(mx, __shfl_xor(mx, m, 32));
  float p = __expf(logit - mx);
  float s = p;
  #pragma unroll
  for (int m = 16; m; m >>= 1) s += __shfl_xor(s, m, 32);
  float prob = p / s;
  // top-1 (tie -> lower index, matches jax top_k)
  float v1 = prob; int i1 = e;
  #pragma unroll
  for (int m = 16; m; m >>= 1) {
    float ov = __shfl_xor(v1, m, 32); int oi = __shfl_xor(i1, m, 32);
    if (ov > v1 || (ov == v1 && oi < i1)) { v1 = ov; i1 = oi; }
  }
  // top-2
  float v2 = (e == i1) ? -1.0f : prob; int i2 = e;
  #pragma unroll
  for (int m = 16; m; m >>= 1) {
    float ov = __shfl_xor(v2, m, 32); int oi = __shfl_xor(i2, m, 32);
    if (ov > v2 || (ov == v2 && oi < i2)) { v2 = ov; i2 = oi; }
  }
  if (e == 0) {
    topk_e[2*t]   = i1; topk_g[2*t]   = v1;   // slot 0
    topk_e[2*t+1] = i2; topk_g[2*t+1] = v2;   // slot 1
    atomicAdd(&counts2[2*i1 + 0], 1);
    atomicAdd(&counts2[2*i2 + 1], 1);
  }
}

// ---------- kernel 2: prefix scan ----------
__global__ void k_scan(const int* __restrict__ counts2, int* __restrict__ eoff,
                       int* __restrict__ c0arr) {
  if (threadIdx.x == 0) {
    int run = 0;
    for (int e = 0; e < E_; e++) {
      eoff[e] = run;
      c0arr[e] = counts2[2*e];
      run += counts2[2*e] + counts2[2*e+1];
    }
    eoff[E_] = run;
  }
}

// ---------- kernel 3: scatter, slot-ordered within each expert ----------
__global__ void k_scatter(const int* __restrict__ topk_e, const float* __restrict__ topk_g,
                          const int* __restrict__ eoff, const int* __restrict__ c0arr,
                          int* __restrict__ cursor2, int* __restrict__ rows, float* __restrict__ gval)
{
  int a = blockIdx.x * 256 + threadIdx.x;   // a < A_
  int t = a >> 1, slot = a & 1;
  int e = topk_e[a];
  int base = eoff[e] + (slot ? c0arr[e] : 0);
  int pos = base + atomicAdd(&cursor2[2*e + slot], 1);
  rows[pos] = t;
  gval[pos] = topk_g[a];
}

// ---------- kernel 4: fc1 grouped GEMM + swiglu (f32 in -> bf16 LDS -> MFMA) ----------
// block tile: 128 rows x 64 h-cols (=128 pre-cols, glu/lin de-interleaved)
// grid: x = E_*MT_MAX, y = I_/64 = 16
__global__ __launch_bounds__(256) void k_fc1(
    const float* __restrict__ x, const float* __restrict__ w1, const float* __restrict__ b1,
    const int* __restrict__ eoff, const int* __restrict__ rows, u16* __restrict__ h)
{
  int e  = blockIdx.x >> 5;          // / MT_MAX
  int mt = blockIdx.x & (MT_MAX-1);
  int seg0 = eoff[e], seg1 = eoff[e+1];
  int count = seg1 - seg0;
  if (mt * 128 >= count) return;
  int base_row = seg0 + mt * 128;
  int valid = count - mt * 128; if (valid > 128) valid = 128;
  int n0h = blockIdx.y * 64;

  __shared__ __align__(16) u16 As[128*64];
  __shared__ __align__(16) u16 Bg[64*64];
  __shared__ __align__(16) u16 Bl[64*64];
  __shared__ int toks[128];

  int tid = threadIdx.x;
  if (tid < 128) {
    int r = (tid < valid) ? tid : 0;
    toks[tid] = rows[base_row + r];
  }
  __syncthreads();

  const float* aptr[4];
  int soA[4];
  #pragma unroll
  for (int i = 0; i < 4; i++) {
    int c = tid + i*256; int r = c >> 3, cc = c & 7;
    aptr[i] = x + (size_t)toks[r] * H_ + cc*8;
    soA[i] = swz(r, cc);
  }
  const float* bgptr[2]; const float* blptr[2];
  int soB[2];
  #pragma unroll
  for (int i = 0; i < 2; i++) {
    int c = tid + i*256; int j = c >> 3, cc = c & 7;
    size_t rowg = (size_t)e * (2*I_) + 2*(n0h + j);   // even channel -> glu
    bgptr[i] = w1 + rowg * H_ + cc*8;
    blptr[i] = bgptr[i] + H_;                          // odd channel -> lin
    soB[i] = swz(j, cc);
  }

  int w = tid >> 6, lane = tid & 63;
  int wm = w >> 1, wn = w & 1;
  int lm = lane & 15, quad = lane >> 4;

  f32x4 zero = {0.f, 0.f, 0.f, 0.f};
  f32x4 accg[4][2], accl[4][2];
  #pragma unroll
  for (int i = 0; i < 4; i++)
    #pragma unroll
    for (int j = 0; j < 2; j++) { accg[i][j] = zero; accl[i][j] = zero; }

  for (int k0 = 0; k0 < H_; k0 += 64) {
    #pragma unroll
    for (int i = 0; i < 4; i++) {
      f32x4 v0 = *(const f32x4*)(aptr[i] + k0);
      f32x4 v1 = *(const f32x4*)(aptr[i] + k0 + 4);
      *(u16x8*)&As[soA[i]] = cvt8(v0, v1);
    }
    #pragma unroll
    for (int i = 0; i < 2; i++) {
      f32x4 g0 = *(const f32x4*)(bgptr[i] + k0);
      f32x4 g1 = *(const f32x4*)(bgptr[i] + k0 + 4);
      f32x4 l0 = *(const f32x4*)(blptr[i] + k0);
      f32x4 l1 = *(const f32x4*)(blptr[i] + k0 + 4);
      *(u16x8*)&Bg[soB[i]] = cvt8(g0, g1);
      *(u16x8*)&Bl[soB[i]] = cvt8(l0, l1);
    }
    __syncthreads();
    #pragma unroll
    for (int kk = 0; kk < 64; kk += 32) {
      bf16x8 af[4], bgf[2], blf[2];
      int cg = (kk >> 3) + quad;   // 8-col group within the 64-wide tile
      #pragma unroll
      for (int i = 0; i < 4; i++)
        af[i] = *(const bf16x8*)&As[swz(wm*64 + i*16 + lm, cg)];
      #pragma unroll
      for (int j = 0; j < 2; j++) {
        int brow = wn*32 + j*16 + lm;
        bgf[j] = *(const bf16x8*)&Bg[swz(brow, cg)];
        blf[j] = *(const bf16x8*)&Bl[swz(brow, cg)];
      }
      #pragma unroll
      for (int i = 0; i < 4; i++)
        #pragma unroll
        for (int j = 0; j < 2; j++) {
          accg[i][j] = __builtin_amdgcn_mfma_f32_16x16x32_bf16(af[i], bgf[j], accg[i][j], 0, 0, 0);
          accl[i][j] = __builtin_amdgcn_mfma_f32_16x16x32_bf16(af[i], blf[j], accl[i][j], 0, 0, 0);
        }
    }
    __syncthreads();
  }

  // epilogue: swiglu, store bf16 h
  #pragma unroll
  for (int i = 0; i < 4; i++) {
    #pragma unroll
    for (int j = 0; j < 2; j++) {
      int colh = n0h + wn*32 + j*16 + lm;
      float bg_ = b1[(size_t)e*(2*I_) + 2*colh];
      float bl_ = b1[(size_t)e*(2*I_) + 2*colh + 1];
      #pragma unroll
      for (int r = 0; r < 4; r++) {
        int rl = wm*64 + i*16 + quad*4 + r;
        if (rl < valid) {
          float g = accg[i][j][r] + bg_;
          float l = accl[i][j][r] + bl_;
          g = fminf(g, 7.0f);
          l = fminf(fmaxf(l, -7.0f), 7.0f);
          float hv = g * (1.0f / (1.0f + __expf(-1.702f * g))) * (l + 1.0f);
          h[(size_t)(base_row + rl) * I_ + colh] = f2bf(hv);
        }
      }
    }
  }
}

// ---------- kernel 5: fc2 grouped GEMM, gated, direct to f32 out ----------
// pass 0: slot-0 sub-segments, out = g*(acc+b2)   (each token exactly once)
// pass 1: slot-1 sub-segments, out += g*(acc+b2)  (sequential launch -> ordered)
// block tile: 128 rows x 128 cols, K = I_ = 1024
// grid: x = E_*MT_MAX, y = H_/128 = 16
__global__ __launch_bounds__(256) void k_fc2(
    const u16* __restrict__ h, const float* __restrict__ w2, const float* __restrict__ b2,
    const int* __restrict__ eoff, const int* __restrict__ c0arr,
    const int* __restrict__ rows, const float* __restrict__ gval,
    float* __restrict__ out, int pass)
{
  int e  = blockIdx.x >> 5;
  int mt = blockIdx.x & (MT_MAX-1);
  int seg0 = eoff[e];
  int c0 = c0arr[e];
  int ctot = eoff[e+1] - seg0;
  int base = seg0 + (pass ? c0 : 0);
  int cnt  = pass ? (ctot - c0) : c0;
  if (mt * 128 >= cnt) return;
  int base_row = base + mt * 128;
  int valid = cnt - mt * 128; if (valid > 128) valid = 128;
  int n0 = blockIdx.y * 128;

  __shared__ __align__(16) u16 As[128*64];
  __shared__ __align__(16) u16 Bs[128*64];

  int tid = threadIdx.x;
  const u16* aptr[4]; const float* bptr[4];
  int soS[4];
  #pragma unroll
  for (int i = 0; i < 4; i++) {
    int c = tid + i*256; int r = c >> 3, cc = c & 7;
    int ar = (r < valid) ? r : 0;
    aptr[i] = h  + (size_t)(base_row + ar) * I_ + cc*8;
    bptr[i] = w2 + ((size_t)e * H_ + n0 + r) * I_ + cc*8;
    soS[i] = swz(r, cc);
  }

  int w = tid >> 6, lane = tid & 63;
  int wm = w >> 1, wn = w & 1;
  int lm = lane & 15, quad = lane >> 4;

  f32x4 zero = {0.f, 0.f, 0.f, 0.f};
  f32x4 acc[4][4];
  #pragma unroll
  for (int i = 0; i < 4; i++)
    #pragma unroll
    for (int j = 0; j < 4; j++) acc[i][j] = zero;

  for (int k0 = 0; k0 < I_; k0 += 64) {
    #pragma unroll
    for (int i = 0; i < 4; i++) {
      u16x8 va = *(const u16x8*)(aptr[i] + k0);           // h already bf16
      f32x4 b0 = *(const f32x4*)(bptr[i] + k0);
      f32x4 b1v = *(const f32x4*)(bptr[i] + k0 + 4);
      *(u16x8*)&As[soS[i]] = va;
      *(u16x8*)&Bs[soS[i]] = cvt8(b0, b1v);
    }
    __syncthreads();
    #pragma unroll
    for (int kk = 0; kk < 64; kk += 32) {
      bf16x8 af[4], bf[4];
      int cg = (kk >> 3) + quad;
      #pragma unroll
      for (int i = 0; i < 4; i++)
        af[i] = *(const bf16x8*)&As[swz(wm*64 + i*16 + lm, cg)];
      #pragma unroll
      for (int j = 0; j < 4; j++)
        bf[j] = *(const bf16x8*)&Bs[swz(wn*64 + j*16 + lm, cg)];
      #pragma unroll
      for (int i = 0; i < 4; i++)
        #pragma unroll
        for (int j = 0; j < 4; j++)
          acc[i][j] = __builtin_amdgcn_mfma_f32_16x16x32_bf16(af[i], bf[j], acc[i][j], 0, 0, 0);
    }
    __syncthreads();
  }

  float bias[4];
  #pragma unroll
  for (int j = 0; j < 4; j++)
    bias[j] = b2[(size_t)e * H_ + n0 + wn*64 + j*16 + lm];

  #pragma unroll
  for (int i = 0; i < 4; i++) {
    #pragma unroll
    for (int r = 0; r < 4; r++) {
      int rl = wm*64 + i*16 + quad*4 + r;
      if (rl < valid) {
        int pos = base_row + rl;
        int t = rows[pos];
        float g = gval[pos];
        #pragma unroll
        for (int j = 0; j < 4; j++) {
          int col = n0 + wn*64 + j*16 + lm;
          size_t oidx = (size_t)t * H_ + col;
          float val = g * (acc[i][j][r] + bias[j]);
          if (pass)
            out[oidx] = out[oidx] + val;
          else
            out[oidx] = val;
        }
      }
    }
  }
}

// ---------- launch ----------
extern "C" void kernel_launch(void* const* d_in, const int* in_sizes, int n_in,
                              void* d_out, int out_size, void* d_ws, size_t ws_size,
                              hipStream_t stream) {
  const float* x  = (const float*)d_in[0];
  const float* gw = (const float*)d_in[1];
  const float* gb = (const float*)d_in[2];
  const float* w1 = (const float*)d_in[3];
  const float* b1 = (const float*)d_in[4];
  const float* w2 = (const float*)d_in[5];
  const float* b2 = (const float*)d_in[6];
  float* out = (float*)d_out;

  char* ws = (char*)d_ws;
  int*   counts2 = (int*)(ws + 0);
  int*   cursor2 = (int*)(ws + 256);
  int*   eoff    = (int*)(ws + 512);
  int*   c0arr   = (int*)(ws + 768);
  int*   topk_e  = (int*)(ws + 1024);
  float* topk_g  = (float*)(ws + 66560);
  int*   rows    = (int*)(ws + 132096);
  float* gval    = (float*)(ws + 197632);
  u16*   hbuf    = (u16*)(ws + 263168);

  k_zero<<<1, 128, 0, stream>>>(counts2);   // counts2 + cursor2 (contiguous 128 ints)
  k_router<<<T_/8, 256, 0, stream>>>(x, gw, gb, counts2, topk_e, topk_g);
  k_scan<<<1, 32, 0, stream>>>(counts2, eoff, c0arr);
  k_scatter<<<A_/256, 256, 0, stream>>>(topk_e, topk_g, eoff, c0arr, cursor2, rows, gval);
  k_fc1<<<dim3(E_*MT_MAX, I_/64), 256, 0, stream>>>(x, w1, b1, eoff, rows, hbuf);
  k_fc2<<<dim3(E_*MT_MAX, H_/128), 256, 0, stream>>>(hbuf, w2, b2, eoff, c0arr, rows, gval, out, 0);
  k_fc2<<<dim3(E_*MT_MAX, H_/128), 256, 0, stream>>>(hbuf, w2, b2, eoff, c0arr, rows, gval, out, 1);
}

// Round 3
// 1876.982 us; speedup vs baseline: 3.2970x; 3.2970x over previous
//
#include <hip/hip_runtime.h>
#include <hip/hip_bf16.h>
#include <stdint.h>

// ---------- problem constants (fixed by setup_inputs) ----------
#define H_  2048      // hidden
#define I_  1024      // intermediate
#define E_  32        // experts
#define T_  8192      // tokens (4*2048)
#define A_  16384     // assignments (T*top_k)

typedef unsigned short u16;
typedef u16  u16x8 __attribute__((ext_vector_type(8)));
typedef __bf16 bf16x8 __attribute__((ext_vector_type(8)));
typedef float f32x4 __attribute__((ext_vector_type(4)));
typedef float f32x8 __attribute__((ext_vector_type(8)));

// native RTNE f32->bf16 (v_cvt_pk_bf16_f32)
__device__ __forceinline__ u16 f2bf(float f) {
  union { __bf16 b; u16 u; } w; w.b = (__bf16)f; return w.u;
}
__device__ __forceinline__ u16x8 cvt8(f32x4 a, f32x4 b) {
  f32x8 f;
  #pragma unroll
  for (int i = 0; i < 4; i++) { f[i] = a[i]; f[i+4] = b[i]; }
  union { bf16x8 h; u16x8 u; } w;
  w.h = __builtin_convertvector(f, bf16x8);
  return w.u;
}

// swizzled u16 index for (row, 8-col-group cc) in a [rows][64]-u16 LDS tile.
// XOR of col-group with (row&7): 16-way read conflict -> 2-way (free).
__device__ __forceinline__ int swz(int r, int cc) {
  return (r << 6) + ((cc ^ (r & 7)) << 3);
}

// ---------- workspace layout (bytes) ----------
// 0      : counts2[64] int   (expert*2 + slot)
// 256    : cursor2[64] int
// 512    : eoff[33]    int
// 768    : c0arr[32]   int
// 1024   : topk_e[A_]  int    -> 66560   (first 2304 B reused as tile maps AFTER k_scatter)
//   1024 : tmap1[192]  int  (built by k_tiles, after topk_e is dead; stream-ordered)
//   1792 : tmap2a[192] int
//   2560 : tmap2b[192] int
// 66560  : topk_g[A_]  float  -> 132096
// 132096 : rows[A_]    int    -> 197632
// 197632 : gval[A_]    float  -> 263168
// 263168 : h[A_*I_]    bf16   -> 33817600
// 33817600 : xbf[T_*H_] bf16  -> 67372032   (only if ws_size permits)

__global__ void k_zero(int* p) { p[threadIdx.x] = 0; }

// ---------- kernel 1: router ----------
__global__ __launch_bounds__(256) void k_router(
    const float* __restrict__ x, const float* __restrict__ gw, const float* __restrict__ gb,
    int* __restrict__ counts2, int* __restrict__ topk_e, float* __restrict__ topk_g)
{
  int tid = threadIdx.x;
  int tt = tid >> 5;          // token within block
  int e  = tid & 31;          // expert
  int t  = blockIdx.x * 8 + tt;
  const float* xp = x  + (size_t)t * H_;
  const float* wp = gw + (size_t)e * H_;
  float acc = 0.f;
  for (int k = 0; k < H_; k += 8) {
    f32x4 x0 = *(const f32x4*)(xp + k);
    f32x4 x1 = *(const f32x4*)(xp + k + 4);
    f32x4 w0 = *(const f32x4*)(wp + k);
    f32x4 w1v = *(const f32x4*)(wp + k + 4);
    #pragma unroll
    for (int i = 0; i < 4; i++) acc += x0[i]*w0[i] + x1[i]*w1v[i];
  }
  float logit = acc + gb[e];
  float mx = logit;
  #pragma unroll
  for (int m = 16; m; m >>= 1) mx = fmaxf(mx, __shfl_xor(mx, m, 32));
  float p = __expf(logit - mx);
  float s = p;
  #pragma unroll
  for (int m = 16; m; m >>= 1) s += __shfl_xor(s, m, 32);
  float prob = p / s;
  float v1 = prob; int i1 = e;
  #pragma unroll
  for (int m = 16; m; m >>= 1) {
    float ov = __shfl_xor(v1, m, 32); int oi = __shfl_xor(i1, m, 32);
    if (ov > v1 || (ov == v1 && oi < i1)) { v1 = ov; i1 = oi; }
  }
  float v2 = (e == i1) ? -1.0f : prob; int i2 = e;
  #pragma unroll
  for (int m = 16; m; m >>= 1) {
    float ov = __shfl_xor(v2, m, 32); int oi = __shfl_xor(i2, m, 32);
    if (ov > v2 || (ov == v2 && oi < i2)) { v2 = ov; i2 = oi; }
  }
  if (e == 0) {
    topk_e[2*t]   = i1; topk_g[2*t]   = v1;
    topk_e[2*t+1] = i2; topk_g[2*t+1] = v2;
    atomicAdd(&counts2[2*i1 + 0], 1);
    atomicAdd(&counts2[2*i2 + 1], 1);
  }
}

// ---------- kernel 2: prefix scan ----------
__global__ void k_scan(const int* __restrict__ counts2, int* __restrict__ eoff,
                       int* __restrict__ c0arr) {
  if (threadIdx.x == 0) {
    int run = 0;
    for (int e = 0; e < E_; e++) {
      eoff[e] = run;
      c0arr[e] = counts2[2*e];
      run += counts2[2*e] + counts2[2*e+1];
    }
    eoff[E_] = run;
  }
}

// ---------- kernel 3: scatter ----------
__global__ void k_scatter(const int* __restrict__ topk_e, const float* __restrict__ topk_g,
                          const int* __restrict__ eoff, const int* __restrict__ c0arr,
                          int* __restrict__ cursor2, int* __restrict__ rows, float* __restrict__ gval)
{
  int a = blockIdx.x * 256 + threadIdx.x;
  int t = a >> 1, slot = a & 1;
  int e = topk_e[a];
  int base = eoff[e] + (slot ? c0arr[e] : 0);
  int pos = base + atomicAdd(&cursor2[2*e + slot], 1);
  rows[pos] = t;
  gval[pos] = topk_g[a];
}

// ---------- kernel 3b: build compact tile maps (after scatter; reuses topk_e space) ----------
__global__ void k_tiles(const int* __restrict__ counts2,
                        int* __restrict__ t1, int* __restrict__ t2a, int* __restrict__ t2b) {
  if (threadIdx.x != 0) return;
  int n1 = 0, n2a = 0, n2b = 0;
  for (int e = 0; e < E_; e++) {
    int c0 = counts2[2*e], c1 = counts2[2*e+1], ct = c0 + c1;
    for (int mt = 0; mt*128 < ct; mt++) t1 [1 + n1++ ] = (e << 8) | mt;
    for (int mt = 0; mt*128 < c0; mt++) t2a[1 + n2a++] = (e << 8) | mt;
    for (int mt = 0; mt*128 < c1; mt++) t2b[1 + n2b++] = (e << 8) | mt;
  }
  t1[0] = n1; t2a[0] = n2a; t2b[0] = n2b;
}

// ---------- kernel 3c: x -> bf16 (once; 33.5 MB, L3-resident afterwards) ----------
__global__ __launch_bounds__(256) void k_cvt_x(const float* __restrict__ x, u16* __restrict__ xbf) {
  size_t i = ((size_t)blockIdx.x * 256 + threadIdx.x) * 8;   // T_*H_/8 threads exactly
  f32x4 a = *(const f32x4*)(x + i);
  f32x4 b = *(const f32x4*)(x + i + 4);
  *(u16x8*)(xbf + i) = cvt8(a, b);
}

// ---------- kernel 4: fc1 grouped GEMM + swiglu ----------
// block tile: 128 rows x 64 h-cols. grid: x = 160 (compact map), y = I_/64 = 16
// ABF: A-side loads bf16 from xbf (no cvt); else legacy f32 gather + cvt.
// A staging is register-staged ds_write to swizzled LDS (round-1-proven; no
// global_load_lds — that mechanism showed a replay-dependent race in round 2).
template<bool ABF>
__global__ __launch_bounds__(256) void k_fc1(
    const float* __restrict__ x, const u16* __restrict__ xbf,
    const float* __restrict__ w1, const float* __restrict__ b1,
    const int* __restrict__ eoff, const int* __restrict__ rows,
    const int* __restrict__ tmap, u16* __restrict__ h)
{
  if ((int)blockIdx.x >= tmap[0]) return;
  int ent = tmap[1 + blockIdx.x];
  int e = ent >> 8, mt = ent & 255;
  int seg0 = eoff[e];
  int count = eoff[e+1] - seg0;
  int base_row = seg0 + mt * 128;
  int valid = count - mt * 128; if (valid > 128) valid = 128;
  int n0h = blockIdx.y * 64;

  __shared__ __align__(16) u16 As[128*64];
  __shared__ __align__(16) u16 Bg[64*64];
  __shared__ __align__(16) u16 Bl[64*64];
  __shared__ int toks[128];

  int tid = threadIdx.x;
  if (tid < 128) {
    int r = (tid < valid) ? tid : 0;
    toks[tid] = rows[base_row + r];
  }
  __syncthreads();

  // A-side addressing (register-staged)
  const u16* agp[4];
  const float* aptr[4];
  int soA[4];
  #pragma unroll
  for (int i = 0; i < 4; i++) {
    int c = tid + i*256; int r = c >> 3, cc = c & 7;
    if (ABF) agp[i]  = xbf + (size_t)toks[r] * H_ + cc*8;
    else     aptr[i] = x   + (size_t)toks[r] * H_ + cc*8;
    soA[i] = swz(r, cc);
  }
  const float* bgptr[2]; const float* blptr[2];
  int soB[2];
  #pragma unroll
  for (int i = 0; i < 2; i++) {
    int c = tid + i*256; int j = c >> 3, cc = c & 7;
    size_t rowg = (size_t)e * (2*I_) + 2*(n0h + j);   // even channel -> glu
    bgptr[i] = w1 + rowg * H_ + cc*8;
    blptr[i] = bgptr[i] + H_;                          // odd channel -> lin
    soB[i] = swz(j, cc);
  }

  int w = tid >> 6, lane = tid & 63;
  int wm = w >> 1, wn = w & 1;
  int lm = lane & 15, quad = lane >> 4;

  f32x4 zero = {0.f, 0.f, 0.f, 0.f};
  f32x4 accg[4][2], accl[4][2];
  #pragma unroll
  for (int i = 0; i < 4; i++)
    #pragma unroll
    for (int j = 0; j < 2; j++) { accg[i][j] = zero; accl[i][j] = zero; }

  for (int k0 = 0; k0 < H_; k0 += 64) {
    if constexpr (ABF) {
      #pragma unroll
      for (int i = 0; i < 4; i++) {
        u16x8 va = *(const u16x8*)(agp[i] + k0);
        *(u16x8*)&As[soA[i]] = va;
      }
    } else {
      #pragma unroll
      for (int i = 0; i < 4; i++) {
        f32x4 v0 = *(const f32x4*)(aptr[i] + k0);
        f32x4 v1 = *(const f32x4*)(aptr[i] + k0 + 4);
        *(u16x8*)&As[soA[i]] = cvt8(v0, v1);
      }
    }
    #pragma unroll
    for (int i = 0; i < 2; i++) {
      f32x4 g0 = *(const f32x4*)(bgptr[i] + k0);
      f32x4 g1 = *(const f32x4*)(bgptr[i] + k0 + 4);
      f32x4 l0 = *(const f32x4*)(blptr[i] + k0);
      f32x4 l1 = *(const f32x4*)(blptr[i] + k0 + 4);
      *(u16x8*)&Bg[soB[i]] = cvt8(g0, g1);
      *(u16x8*)&Bl[soB[i]] = cvt8(l0, l1);
    }
    __syncthreads();
    #pragma unroll
    for (int kk = 0; kk < 64; kk += 32) {
      bf16x8 af[4], bgf[2], blf[2];
      int cg = (kk >> 3) + quad;
      #pragma unroll
      for (int i = 0; i < 4; i++)
        af[i] = *(const bf16x8*)&As[swz(wm*64 + i*16 + lm, cg)];
      #pragma unroll
      for (int j = 0; j < 2; j++) {
        int brow = wn*32 + j*16 + lm;
        bgf[j] = *(const bf16x8*)&Bg[swz(brow, cg)];
        blf[j] = *(const bf16x8*)&Bl[swz(brow, cg)];
      }
      #pragma unroll
      for (int i = 0; i < 4; i++)
        #pragma unroll
        for (int j = 0; j < 2; j++) {
          accg[i][j] = __builtin_amdgcn_mfma_f32_16x16x32_bf16(af[i], bgf[j], accg[i][j], 0, 0, 0);
          accl[i][j] = __builtin_amdgcn_mfma_f32_16x16x32_bf16(af[i], blf[j], accl[i][j], 0, 0, 0);
        }
    }
    __syncthreads();
  }

  #pragma unroll
  for (int i = 0; i < 4; i++) {
    #pragma unroll
    for (int j = 0; j < 2; j++) {
      int colh = n0h + wn*32 + j*16 + lm;
      float bg_ = b1[(size_t)e*(2*I_) + 2*colh];
      float bl_ = b1[(size_t)e*(2*I_) + 2*colh + 1];
      #pragma unroll
      for (int r = 0; r < 4; r++) {
        int rl = wm*64 + i*16 + quad*4 + r;
        if (rl < valid) {
          float g = accg[i][j][r] + bg_;
          float l = accl[i][j][r] + bl_;
          g = fminf(g, 7.0f);
          l = fminf(fmaxf(l, -7.0f), 7.0f);
          float hv = g * (1.0f / (1.0f + __expf(-1.702f * g))) * (l + 1.0f);
          h[(size_t)(base_row + rl) * I_ + colh] = f2bf(hv);
        }
      }
    }
  }
}

// ---------- kernel 5: fc2 grouped GEMM, gated ----------
// A-side (h, already bf16) register-staged to swizzled LDS.
__global__ __launch_bounds__(256) void k_fc2(
    const u16* __restrict__ h, const float* __restrict__ w2, const float* __restrict__ b2,
    const int* __restrict__ eoff, const int* __restrict__ c0arr,
    const int* __restrict__ rows, const float* __restrict__ gval,
    const int* __restrict__ tmap, float* __restrict__ out, int pass)
{
  if ((int)blockIdx.x >= tmap[0]) return;
  int ent = tmap[1 + blockIdx.x];
  int e = ent >> 8, mt = ent & 255;
  int seg0 = eoff[e];
  int c0 = c0arr[e];
  int ctot = eoff[e+1] - seg0;
  int base = seg0 + (pass ? c0 : 0);
  int cnt  = pass ? (ctot - c0) : c0;
  int base_row = base + mt * 128;
  int valid = cnt - mt * 128; if (valid > 128) valid = 128;
  int n0 = blockIdx.y * 128;

  __shared__ __align__(16) u16 As[128*64];
  __shared__ __align__(16) u16 Bs[128*64];

  int tid = threadIdx.x;
  const u16* aptr[4]; const float* bptr[4];
  int soS[4];
  #pragma unroll
  for (int i = 0; i < 4; i++) {
    int c = tid + i*256; int r = c >> 3, cc = c & 7;
    int ar = (r < valid) ? r : 0;
    aptr[i] = h  + (size_t)(base_row + ar) * I_ + cc*8;
    bptr[i] = w2 + ((size_t)e * H_ + n0 + r) * I_ + cc*8;
    soS[i] = swz(r, cc);
  }

  int w = tid >> 6, lane = tid & 63;
  int wm = w >> 1, wn = w & 1;
  int lm = lane & 15, quad = lane >> 4;

  f32x4 zero = {0.f, 0.f, 0.f, 0.f};
  f32x4 acc[4][4];
  #pragma unroll
  for (int i = 0; i < 4; i++)
    #pragma unroll
    for (int j = 0; j < 4; j++) acc[i][j] = zero;

  for (int k0 = 0; k0 < I_; k0 += 64) {
    #pragma unroll
    for (int i = 0; i < 4; i++) {
      u16x8 va = *(const u16x8*)(aptr[i] + k0);           // h already bf16
      f32x4 b0 = *(const f32x4*)(bptr[i] + k0);
      f32x4 b1v = *(const f32x4*)(bptr[i] + k0 + 4);
      *(u16x8*)&As[soS[i]] = va;
      *(u16x8*)&Bs[soS[i]] = cvt8(b0, b1v);
    }
    __syncthreads();
    #pragma unroll
    for (int kk = 0; kk < 64; kk += 32) {
      bf16x8 af[4], bf[4];
      int cg = (kk >> 3) + quad;
      #pragma unroll
      for (int i = 0; i < 4; i++)
        af[i] = *(const bf16x8*)&As[swz(wm*64 + i*16 + lm, cg)];
      #pragma unroll
      for (int j = 0; j < 4; j++)
        bf[j] = *(const bf16x8*)&Bs[swz(wn*64 + j*16 + lm, cg)];
      #pragma unroll
      for (int i = 0; i < 4; i++)
        #pragma unroll
        for (int j = 0; j < 4; j++)
          acc[i][j] = __builtin_amdgcn_mfma_f32_16x16x32_bf16(af[i], bf[j], acc[i][j], 0, 0, 0);
    }
    __syncthreads();
  }

  float bias[4];
  #pragma unroll
  for (int j = 0; j < 4; j++)
    bias[j] = b2[(size_t)e * H_ + n0 + wn*64 + j*16 + lm];

  #pragma unroll
  for (int i = 0; i < 4; i++) {
    #pragma unroll
    for (int r = 0; r < 4; r++) {
      int rl = wm*64 + i*16 + quad*4 + r;
      if (rl < valid) {
        int pos = base_row + rl;
        int t = rows[pos];
        float g = gval[pos];
        #pragma unroll
        for (int j = 0; j < 4; j++) {
          int col = n0 + wn*64 + j*16 + lm;
          size_t oidx = (size_t)t * H_ + col;
          float val = g * (acc[i][j][r] + bias[j]);
          if (pass)
            out[oidx] = out[oidx] + val;
          else
            out[oidx] = val;
        }
      }
    }
  }
}

// ---------- launch ----------
extern "C" void kernel_launch(void* const* d_in, const int* in_sizes, int n_in,
                              void* d_out, int out_size, void* d_ws, size_t ws_size,
                              hipStream_t stream) {
  const float* x  = (const float*)d_in[0];
  const float* gw = (const float*)d_in[1];
  const float* gb = (const float*)d_in[2];
  const float* w1 = (const float*)d_in[3];
  const float* b1 = (const float*)d_in[4];
  const float* w2 = (const float*)d_in[5];
  const float* b2 = (const float*)d_in[6];
  float* out = (float*)d_out;

  char* ws = (char*)d_ws;
  int*   counts2 = (int*)(ws + 0);
  int*   cursor2 = (int*)(ws + 256);
  int*   eoff    = (int*)(ws + 512);
  int*   c0arr   = (int*)(ws + 768);
  int*   topk_e  = (int*)(ws + 1024);
  int*   tmap1   = (int*)(ws + 1024);      // reuses topk_e space AFTER k_scatter
  int*   tmap2a  = (int*)(ws + 1792);
  int*   tmap2b  = (int*)(ws + 2560);
  float* topk_g  = (float*)(ws + 66560);
  int*   rows    = (int*)(ws + 132096);
  float* gval    = (float*)(ws + 197632);
  u16*   hbuf    = (u16*)(ws + 263168);
  u16*   xbf     = (u16*)(ws + 33817600);
  bool has_xbf = ws_size >= (size_t)33817600 + (size_t)T_ * H_ * 2;

  k_zero<<<1, 128, 0, stream>>>(counts2);
  k_router<<<T_/8, 256, 0, stream>>>(x, gw, gb, counts2, topk_e, topk_g);
  k_scan<<<1, 32, 0, stream>>>(counts2, eoff, c0arr);
  k_scatter<<<A_/256, 256, 0, stream>>>(topk_e, topk_g, eoff, c0arr, cursor2, rows, gval);
  k_tiles<<<1, 32, 0, stream>>>(counts2, tmap1, tmap2a, tmap2b);
  if (has_xbf) {
    k_cvt_x<<<(T_*H_/8)/256, 256, 0, stream>>>(x, xbf);
    k_fc1<true><<<dim3(160, I_/64), 256, 0, stream>>>(x, xbf, w1, b1, eoff, rows, tmap1, hbuf);
  } else {
    k_fc1<false><<<dim3(160, I_/64), 256, 0, stream>>>(x, xbf, w1, b1, eoff, rows, tmap1, hbuf);
  }
  k_fc2<<<dim3(160, H_/128), 256, 0, stream>>>(hbuf, w2, b2, eoff, c0arr, rows, gval, tmap2a, out, 0);
  k_fc2<<<dim3(160, H_/128), 256, 0, stream>>>(hbuf, w2, b2, eoff, c0arr, rows, gval, tmap2b, out, 1);
}